// Round 8
// baseline (255.961 us; speedup 1.0000x reference)
//
#include <hip/hip_runtime.h>
#include <math.h>

constexpr int B = 2, C = 64, H = 80, W = 80, HW = H * W, COUT = 64;

typedef __attribute__((ext_vector_type(8))) short short8;   // 8 bf16
typedef __attribute__((ext_vector_type(4))) float f32x4;
typedef __attribute__((ext_vector_type(2))) float f32x2;
typedef __attribute__((ext_vector_type(4))) int i32x4;

__device__ inline ushort f2bf(float f) {
  unsigned u = __float_as_uint(f);
  unsigned r = u + 0x7fff + ((u >> 16) & 1);   // RNE
  return (ushort)(r >> 16);
}

__device__ inline f32x2 unpack_bf2(unsigned u) {
  f32x2 r;
  r.x = __uint_as_float(u << 16);
  r.y = __uint_as_float(u & 0xffff0000u);
  return r;
}

// bilinear-combine 2 bf16 channels x 4 corners, repack to 2 bf16 (1 v_perm)
__device__ inline unsigned bilin_pack(unsigned a, unsigned b, unsigned c,
                                      unsigned d, f32x2 c00, f32x2 c01,
                                      f32x2 c10, f32x2 c11) {
  f32x2 p = unpack_bf2(a) * c00;
  p += unpack_bf2(b) * c01;
  p += unpack_bf2(c) * c10;
  p += unpack_bf2(d) * c11;
  unsigned lo = __float_as_uint(p.x) + 0x8000u;
  unsigned hi = __float_as_uint(p.y) + 0x8000u;
  return __builtin_amdgcn_perm(hi, lo, 0x07060302);
}

// ---------------------------------------------------------------------------
// Weight prep body (grid-stride over this branch's swizzled tables).
// ---------------------------------------------------------------------------
template <int K, int NT>
__device__ void prep_body(int pb, int nblk, const float* __restrict__ w_off,
                          const float* __restrict__ b_off,
                          const float* __restrict__ w_mask,
                          const float* __restrict__ b_mask,
                          const float* __restrict__ w_dcn,
                          ushort* __restrict__ wtbs, float* __restrict__ bcomb,
                          ushort* __restrict__ wdts) {
  constexpr int KK = K * K, C3 = 3 * KK;
  const int n1 = KK * 2 * NT * 512;
  const int n2 = C3;
  const int n3 = KK * 2 * 4 * 512;
  const int total = n1 + n2 + n3;
  for (int i = pb * 256 + threadIdx.x; i < total; i += nblk * 256) {
    if (i < n1) {
      int e = i & 7, l = (i >> 3) & 63;
      int blk512 = i >> 9;
      int nt = blk512 % NT, th = blk512 / NT;
      int half = th & 1, t = th >> 1;
      int n = nt * 16 + (l & 15);
      int ci = half * 32 + (l >> 4) * 8 + e;
      float v = 0.f;
      if (n < 2 * KK) v = w_off[(n * C + ci) * KK + t];
      else if (n < C3) v = w_mask[((n - 2 * KK) * C + ci) * KK + t];
      wtbs[i] = f2bf(v);
    } else if (i < n1 + n2) {
      int co = i - n1;
      bcomb[co] = (co < 2 * KK) ? b_off[co] : b_mask[co - 2 * KK];
    } else {
      int j = i - n1 - n2;
      int e = j & 7, l = (j >> 3) & 63;
      int blk512 = j >> 9;
      int jt = blk512 & 3, th = blk512 >> 2;
      int half = th & 1, t = th >> 1;
      int co = jt * 16 + (l & 15);
      int ci = half * 32 + (l >> 4) * 8 + e;
      wdts[j] = f2bf(w_dcn[(co * C + ci) * KK + t]);
    }
  }
}

// ---------------------------------------------------------------------------
// setup_all: blocks 0..199 transpose NCHW->NHWC bf16 (+zero row); rest prep.
// ---------------------------------------------------------------------------
__global__ __launch_bounds__(256) void setup_all(
    const float* __restrict__ x, ushort* __restrict__ xhb,
    const float* __restrict__ w_off3, const float* __restrict__ b_off3,
    const float* __restrict__ w_mask3, const float* __restrict__ b_mask3,
    const float* __restrict__ w_dcn3, ushort* __restrict__ wtbs3,
    float* __restrict__ bc3, ushort* __restrict__ wdts3,
    const float* __restrict__ w_off5, const float* __restrict__ b_off5,
    const float* __restrict__ w_mask5, const float* __restrict__ b_mask5,
    const float* __restrict__ w_dcn5, ushort* __restrict__ wtbs5,
    float* __restrict__ bc5, ushort* __restrict__ wdts5,
    const float* __restrict__ w_off7, const float* __restrict__ b_off7,
    const float* __restrict__ w_mask7, const float* __restrict__ b_mask7,
    const float* __restrict__ w_dcn7, ushort* __restrict__ wtbs7,
    float* __restrict__ bc7, ushort* __restrict__ wdts7) {
  __shared__ float tile[64][65];
  int blk = blockIdx.x;
  if (blk < 200) {
    int b = blk / (HW / 64);
    int p0 = (blk % (HW / 64)) * 64;
    int lane = threadIdx.x & 63, row = threadIdx.x >> 6;
    if (blk == 0 && threadIdx.x < 64)
      xhb[(size_t)B * HW * C + threadIdx.x] = 0;   // zero row for OOB loads
#pragma unroll
    for (int it = 0; it < 16; ++it) {
      int ci = it * 4 + row;
      tile[ci][lane] = x[(size_t)(b * C + ci) * HW + p0 + lane];
    }
    __syncthreads();
#pragma unroll
    for (int it = 0; it < 16; ++it) {
      int pl = it * 4 + row;
      xhb[((size_t)b * HW + p0 + pl) * C + lane] = f2bf(tile[lane][pl]);
    }
  } else {
    int pb = blk - 200;
    prep_body<7, 10>(pb, 256, w_off7, b_off7, w_mask7, b_mask7, w_dcn7, wtbs7,
                     bc7, wdts7);
    prep_body<5, 6>(pb, 256, w_off5, b_off5, w_mask5, b_mask5, w_dcn5, wtbs5,
                    bc5, wdts5);
    prep_body<3, 2>(pb, 256, w_off3, b_off3, w_mask3, b_mask3, w_dcn3, wtbs3,
                    bc3, wdts3);
  }
}

// ---------------------------------------------------------------------------
// Conv body: implicit-im2col bf16 MFMA GEMM, 2-stage software pipeline with
// sched_barrier pinning; OOB handled by zero-row redirect.
// ---------------------------------------------------------------------------
template <int K, int NT, int NTA, int MB>
__device__ __forceinline__ void conv_body(int blk,
                                          const ushort* __restrict__ xhb,
                                          const ushort* __restrict__ wtbs,
                                          const float* __restrict__ bcomb,
                                          float* __restrict__ convout) {
  constexpr int PAD = K / 2, KK = K * K, C3 = 3 * KK;
  constexpr int NG = NT / NTA;
  static_assert(NG * NTA == NT, "exact n-split");
  const int ZPIX = B * HW;                 // zero-row pixel index
  int tid = threadIdx.x;
  int wid = blk * 4 + (tid >> 6);
  int mt = wid / NG;
  int g = wid % NG;
  int j0 = g * NTA;
  int l = tid & 63;
  int lm = l & 15, lk = l >> 4;
  int m0 = mt * (16 * MB);
  int b = m0 / HW;
  int y[MB], x0[MB];
#pragma unroll
  for (int i = 0; i < MB; ++i) {
    int rem = (m0 + 16 * i) % HW;
    y[i] = rem / W;
    x0[i] = rem % W;                       // 16 | W -> tile stays in one row
  }
  f32x4 acc[MB][NTA];
#pragma unroll
  for (int i = 0; i < MB; ++i)
#pragma unroll
    for (int j = 0; j < NTA; ++j) acc[i][j] = f32x4{0.f, 0.f, 0.f, 0.f};

  short8 A0[2][MB], A1[2][MB], Bf0[2][NTA], Bf1[2][NTA];

  auto load_tap = [&](int t, int s) {
    int ky = t / K, kx = t % K;
#pragma unroll
    for (int i = 0; i < MB; ++i) {
      int yy = y[i] + ky - PAD;
      int xx = x0[i] + lm + kx - PAD;
      bool v = ((unsigned)yy < (unsigned)H) && ((unsigned)xx < (unsigned)W);
      int pidx = b * HW + yy * W + xx;
      const ushort* ap = xhb + (size_t)(v ? pidx : ZPIX) * C + lk * 8;
      A0[s][i] = *(const short8*)ap;
      A1[s][i] = *(const short8*)(ap + 32);
    }
    const ushort* fbase = wtbs + (size_t)(t * 2) * NT * 512 + l * 8;
#pragma unroll
    for (int jj = 0; jj < NTA; ++jj) {
      Bf0[s][jj] = *(const short8*)(fbase + (size_t)(j0 + jj) * 512);
      Bf1[s][jj] = *(const short8*)(fbase + (size_t)(NT + j0 + jj) * 512);
    }
  };

  load_tap(0, 0);
#pragma unroll
  for (int t = 0; t < KK; ++t) {
    int s = t & 1;
    if (t + 1 < KK) load_tap(t + 1, s ^ 1);
    __builtin_amdgcn_sched_barrier(0);   // pin: prefetch issues stay above
#pragma unroll
    for (int jj = 0; jj < NTA; ++jj)
#pragma unroll
      for (int i = 0; i < MB; ++i)
        acc[i][jj] = __builtin_amdgcn_mfma_f32_16x16x32_bf16(A0[s][i], Bf0[s][jj],
                                                            acc[i][jj], 0, 0, 0);
#pragma unroll
    for (int jj = 0; jj < NTA; ++jj)
#pragma unroll
      for (int i = 0; i < MB; ++i)
        acc[i][jj] = __builtin_amdgcn_mfma_f32_16x16x32_bf16(A1[s][i], Bf1[s][jj],
                                                            acc[i][jj], 0, 0, 0);
  }

  // Epilogue. D mapping: col(n)=lm, row(m)=lk*4+r.
#pragma unroll
  for (int i = 0; i < MB; ++i) {
#pragma unroll
    for (int jj = 0; jj < NTA; ++jj) {
      int co = (j0 + jj) * 16 + lm;
      if (co >= C3) continue;              // only k=5 padding hits this
      float bs = bcomb[co];
      bool isoff = co < 2 * KK;
      int tp = co >> 1;
#pragma unroll
      for (int r = 0; r < 4; ++r) {
        int xr = x0[i] + lk * 4 + r;
        int pix = m0 + 16 * i + lk * 4 + r;
        float v = acc[i][jj][r] + bs;
        if (isoff) {
          v += (co & 1) ? (float)(xr - PAD + tp % K)    // px
                        : (float)(y[i] - PAD + tp / K); // py
        } else {
          v = 1.f / (1.f + expf(-v));
        }
        convout[(size_t)pix * C3 + co] = v;
      }
    }
  }
}

__global__ __launch_bounds__(256, 3) void conv_all(
    const ushort* __restrict__ xhb,
    const ushort* __restrict__ wtbs7, const float* __restrict__ bc7, float* __restrict__ co7,
    const ushort* __restrict__ wtbs5, const float* __restrict__ bc5, float* __restrict__ co5,
    const ushort* __restrict__ wtbs3, const float* __restrict__ bc3, float* __restrict__ co3) {
  int blk = blockIdx.x;
  if (blk < 500) conv_body<7, 10, 2, 2>(blk, xhb, wtbs7, bc7, co7);           // NG=5
  else if (blk < 700) conv_body<5, 6, 3, 2>(blk - 500, xhb, wtbs5, bc5, co5); // NG=2
  else conv_body<3, 2, 2, 2>(blk - 700, xhb, wtbs3, bc3, co3);                // NG=1
}

// ---------------------------------------------------------------------------
// DCN body: one-time LDS meta table (mask-folded coeffs + clamped byte
// offsets for every (pixel, tap)), then a branch-free pinned 2-stage
// pipelined tap loop: 2x ds_read_b128 -> 8 gathers -> pack -> 8 MFMA.
// ---------------------------------------------------------------------------
template <int K>
__device__ __forceinline__ void dcn_body(int blk, const ushort* __restrict__ xhb,
                                         const float* __restrict__ convout,
                                         const ushort* __restrict__ wdts,
                                         float* __restrict__ out, int br_off,
                                         float* s_buf, float* s_meta) {
  constexpr int KK = K * K, C3 = 3 * KK;
  constexpr int TPW = (KK + 3) / 4;
  constexpr int TAPS4 = TPW * 4;
  int tid = threadIdx.x, w = tid >> 6, l = tid & 63;
  int lm = l & 15, lk = l >> 4;
  int m0 = blk * 16;
  int b = m0 / HW;
  const ushort* xb = xhb + (size_t)b * HW * C;
  const char* xc = (const char*)xb;
  // Phase 1: stage conv output (py/px/mask) into LDS
  for (int idx = tid; idx < 16 * C3; idx += 256)
    s_buf[idx] = convout[(size_t)m0 * C3 + idx];
  __syncthreads();
  // Phase 2: build meta table for all (pix, tap) incl. dummy padding taps
  for (int idx = tid; idx < 16 * TAPS4; idx += 256) {
    int pix = idx / TAPS4, t = idx - pix * TAPS4;
    const float* cp = s_buf + pix * C3;
    bool tv = t < KK;
    int ts = tv ? t : 0;
    float py = cp[2 * ts], px = cp[2 * ts + 1];
    float m = tv ? cp[2 * KK + ts] : 0.f;  // dummy taps contribute exactly 0
    float fy = floorf(py), fx = floorf(px);
    float wy1 = py - fy, wx1 = px - fx;
    float wy0 = 1.f - wy1, wx0 = 1.f - wx1;
    int y0 = (int)fy, x0 = (int)fx;
    int y1 = y0 + 1, x1 = x0 + 1;
    bool vy0 = (unsigned)y0 < (unsigned)H, vy1 = (unsigned)y1 < (unsigned)H;
    bool vx0 = (unsigned)x0 < (unsigned)W, vx1 = (unsigned)x1 < (unsigned)W;
    float* mp = s_meta + (size_t)idx * 8;
    mp[0] = m * wy0 * wx0 * ((vy0 & vx0) ? 1.f : 0.f);
    mp[1] = m * wy0 * wx1 * ((vy0 & vx1) ? 1.f : 0.f);
    mp[2] = m * wy1 * wx0 * ((vy1 & vx0) ? 1.f : 0.f);
    mp[3] = m * wy1 * wx1 * ((vy1 & vx1) ? 1.f : 0.f);
    int y0c = min(max(y0, 0), H - 1), y1c = min(max(y1, 0), H - 1);
    int x0c = min(max(x0, 0), W - 1), x1c = min(max(x1, 0), W - 1);
    int* ip = (int*)(mp + 4);
    ip[0] = (y0c * W + x0c) * C * 2;       // byte offsets into xb
    ip[1] = (y0c * W + x1c) * C * 2;
    ip[2] = (y1c * W + x0c) * C * 2;
    ip[3] = (y1c * W + x1c) * C * 2;
  }
  __syncthreads();

  f32x4 acc[4];
#pragma unroll
  for (int j = 0; j < 4; ++j) acc[j] = f32x4{0.f, 0.f, 0.f, 0.f};

  int cb = lk * 16;                        // byte offset of this lane's chans
  uint4 U[2][8];
  f32x4 CF[2];

  auto load_tap = [&](int tt, int s) {
    int t = w * TPW + tt;
    const float* mp = s_meta + ((size_t)lm * TAPS4 + t) * 8;
    f32x4 cf = *(const f32x4*)mp;
    i32x4 of = *(const i32x4*)(mp + 4);
    CF[s] = cf;
    U[s][0] = *(const uint4*)(xc + of.x + cb);
    U[s][1] = *(const uint4*)(xc + of.x + cb + 64);
    U[s][2] = *(const uint4*)(xc + of.y + cb);
    U[s][3] = *(const uint4*)(xc + of.y + cb + 64);
    U[s][4] = *(const uint4*)(xc + of.z + cb);
    U[s][5] = *(const uint4*)(xc + of.z + cb + 64);
    U[s][6] = *(const uint4*)(xc + of.w + cb);
    U[s][7] = *(const uint4*)(xc + of.w + cb + 64);
  };

  load_tap(0, 0);
#pragma unroll
  for (int tt = 0; tt < TPW; ++tt) {
    int s = tt & 1;
    if (tt + 1 < TPW) load_tap(tt + 1, s ^ 1);
    __builtin_amdgcn_sched_barrier(0);   // pin: prefetch issues stay above
    int t = w * TPW + tt;
    int ts = (t < KK) ? t : 0;           // wave-uniform clamp for B address
    f32x2 c00 = {CF[s][0], CF[s][0]}, c01 = {CF[s][1], CF[s][1]};
    f32x2 c10 = {CF[s][2], CF[s][2]}, c11 = {CF[s][3], CF[s][3]};
    uint4 apa, apb;
    apa.x = bilin_pack(U[s][0].x, U[s][2].x, U[s][4].x, U[s][6].x, c00, c01, c10, c11);
    apa.y = bilin_pack(U[s][0].y, U[s][2].y, U[s][4].y, U[s][6].y, c00, c01, c10, c11);
    apa.z = bilin_pack(U[s][0].z, U[s][2].z, U[s][4].z, U[s][6].z, c00, c01, c10, c11);
    apa.w = bilin_pack(U[s][0].w, U[s][2].w, U[s][4].w, U[s][6].w, c00, c01, c10, c11);
    apb.x = bilin_pack(U[s][1].x, U[s][3].x, U[s][5].x, U[s][7].x, c00, c01, c10, c11);
    apb.y = bilin_pack(U[s][1].y, U[s][3].y, U[s][5].y, U[s][7].y, c00, c01, c10, c11);
    apb.z = bilin_pack(U[s][1].z, U[s][3].z, U[s][5].z, U[s][7].z, c00, c01, c10, c11);
    apb.w = bilin_pack(U[s][1].w, U[s][3].w, U[s][5].w, U[s][7].w, c00, c01, c10, c11);
    short8 aa = *(short8*)&apa;
    short8 ab = *(short8*)&apb;
    const ushort* fb0 = wdts + (size_t)((ts * 2 + 0) * 4) * 512 + l * 8;
    const ushort* fb1 = wdts + (size_t)((ts * 2 + 1) * 4) * 512 + l * 8;
#pragma unroll
    for (int j = 0; j < 4; ++j) {
      short8 bf = *(const short8*)(fb0 + j * 512);
      acc[j] = __builtin_amdgcn_mfma_f32_16x16x32_bf16(aa, bf, acc[j], 0, 0, 0);
    }
#pragma unroll
    for (int j = 0; j < 4; ++j) {
      short8 bf = *(const short8*)(fb1 + j * 512);
      acc[j] = __builtin_amdgcn_mfma_f32_16x16x32_bf16(ab, bf, acc[j], 0, 0, 0);
    }
  }

  __syncthreads();   // meta/s_buf reads done before s_red overwrites
  float (*s_red)[16][65] = (float (*)[16][65])s_buf;
#pragma unroll
  for (int j = 0; j < 4; ++j)
#pragma unroll
    for (int r = 0; r < 4; ++r)
      s_red[w][lk * 4 + r][j * 16 + lm] = acc[j][r];
  __syncthreads();
  int rem0 = m0 - b * HW;
#pragma unroll
  for (int i = 0; i < 4; ++i) {
    int idx = i * 256 + tid;
    int mrow = idx & 15, co = idx >> 4;
    float v = s_red[0][mrow][co] + s_red[1][mrow][co] +
              s_red[2][mrow][co] + s_red[3][mrow][co];
    out[(size_t)(b * (3 * COUT) + br_off + co) * HW + rem0 + mrow] = v;
  }
}

__global__ __launch_bounds__(256, 3) void dcn_all(
    const ushort* __restrict__ xhb,
    const float* __restrict__ co7, const ushort* __restrict__ wdts7,
    const float* __restrict__ co5, const ushort* __restrict__ wdts5,
    const float* __restrict__ co3, const ushort* __restrict__ wdts3,
    float* __restrict__ out) {
  // s_buf: union of conv-staging (<=2352 f) and s_red (4160 f) = 4160 floats
  // s_meta: 16 * TAPS4max(52) * 8 = 6656 floats. Total 43.3 KB.
  __shared__ float smem[4160 + 16 * 52 * 8];
  float* s_buf = smem;
  float* s_meta = smem + 4160;
  int blk = blockIdx.x;
  if (blk < 800) dcn_body<7>(blk, xhb, co7, wdts7, out, 128, s_buf, s_meta);
  else if (blk < 1600) dcn_body<5>(blk - 800, xhb, co5, wdts5, out, 64, s_buf, s_meta);
  else dcn_body<3>(blk - 1600, xhb, co3, wdts3, out, 0, s_buf, s_meta);
}

// ---------------------------------------------------------------------------
// Launch
// ---------------------------------------------------------------------------
extern "C" void kernel_launch(void* const* d_in, const int* in_sizes, int n_in,
                              void* d_out, int out_size, void* d_ws,
                              size_t ws_size, hipStream_t stream) {
  const float* x = (const float*)d_in[0];
  const float* w_off3 = (const float*)d_in[1];
  const float* b_off3 = (const float*)d_in[2];
  const float* w_mask3 = (const float*)d_in[3];
  const float* b_mask3 = (const float*)d_in[4];
  const float* w_dcn3 = (const float*)d_in[5];
  const float* w_off5 = (const float*)d_in[6];
  const float* b_off5 = (const float*)d_in[7];
  const float* w_mask5 = (const float*)d_in[8];
  const float* b_mask5 = (const float*)d_in[9];
  const float* w_dcn5 = (const float*)d_in[10];
  const float* w_off7 = (const float*)d_in[11];
  const float* b_off7 = (const float*)d_in[12];
  const float* w_mask7 = (const float*)d_in[13];
  const float* b_mask7 = (const float*)d_in[14];
  const float* w_dcn7 = (const float*)d_in[15];
  float* out = (float*)d_out;
  float* ws = (float*)d_ws;

  // Workspace layout (float units, 16B aligned)
  size_t off = 0;
  auto alloc = [&](size_t n) {
    size_t p = off;
    off += (n + 3) & ~(size_t)3;
    return ws + p;
  };
  ushort* xhb = (ushort*)alloc((size_t)B * HW * C / 2 + 64);  // +zero row
  float* co3 = alloc((size_t)B * HW * 27);
  float* co5 = alloc((size_t)B * HW * 75);
  float* co7 = alloc((size_t)B * HW * 147);
  ushort* wtbs3 = (ushort*)alloc(9 * 2 * 2 * 512 / 2);
  ushort* wtbs5 = (ushort*)alloc(25 * 2 * 6 * 512 / 2);
  ushort* wtbs7 = (ushort*)alloc(49 * 2 * 10 * 512 / 2);
  float* bc3 = alloc(27);
  float* bc5 = alloc(75);
  float* bc7 = alloc(147);
  ushort* wdts3 = (ushort*)alloc(9 * 2 * 4 * 512 / 2);
  ushort* wdts5 = (ushort*)alloc(25 * 2 * 4 * 512 / 2);
  ushort* wdts7 = (ushort*)alloc(49 * 2 * 4 * 512 / 2);

  // 1) transpose + all weight prep (one launch)
  setup_all<<<456, 256, 0, stream>>>(
      x, xhb,
      w_off3, b_off3, w_mask3, b_mask3, w_dcn3, wtbs3, bc3, wdts3,
      w_off5, b_off5, w_mask5, b_mask5, w_dcn5, wtbs5, bc5, wdts5,
      w_off7, b_off7, w_mask7, b_mask7, w_dcn7, wtbs7, bc7, wdts7);

  // 2) all offset+mask convs (one launch; k=7 500 blocks, k=5 200, k=3 100)
  conv_all<<<800, 256, 0, stream>>>(xhb, wtbs7, bc7, co7, wtbs5, bc5, co5,
                                    wtbs3, bc3, co3);

  // 3) all fused deformable sampling + einsum (one launch, k=7 first)
  dcn_all<<<2400, 256, 0, stream>>>(xhb, co7, wdts7, co5, wdts5, co3, wdts3,
                                    out);
}